// Round 4
// baseline (851.804 us; speedup 1.0000x reference)
//
#include <hip/hip_runtime.h>
#include <hip/hip_bf16.h>

// ---------------------------------------------------------------------------
// VQ-VAE forward. All GEMM operands pre-tiled to MFMA-ready layout
// [panel][kbg][128][8] (panel = 128 rows/cols, kbg = 8 k's), staged via
// global_load_lds dwordx4. Encoder split-bf16 (3-MFMA), decoder plain bf16.
// ---------------------------------------------------------------------------

typedef __attribute__((ext_vector_type(8))) short short8v;
typedef __attribute__((ext_vector_type(4))) float f32x4;

__device__ inline ushort f2bf(float v) {
    __hip_bfloat16 h = __float2bfloat16(v);
    return *reinterpret_cast<ushort*>(&h);
}
__device__ inline float bf2f(ushort s) {
    __hip_bfloat16 h;
    *reinterpret_cast<ushort*>(&h) = s;
    return __bfloat162float(h);
}

// copy 8192 B (one K-step tile: 4 kb-blocks of [128][8] bf16) global -> LDS.
// Layouts are identical, so this is a pure linear DMA: 8 chunks of 1024 B,
// 4 waves x 2 issues, lane l writes lds chunk_base + l*16.
__device__ __forceinline__ void stage_tile(const ushort* __restrict__ src,
                                           ushort* dst, int wid, int lane)
{
#pragma unroll
    for (int j = 0; j < 2; ++j) {
        const int ci = (j << 2) + wid;
        __builtin_amdgcn_global_load_lds(
            (const __attribute__((address_space(1))) unsigned int*)(src + ci * 512 + lane * 8),
            (__attribute__((address_space(3))) unsigned int*)(dst + ci * 512),
            16, 0, 0);
    }
}

// ---------------------------------------------------------------------------
// MFMA GEMM on tiled operands. A: [rb][kbgA][128][8] (+lo if SPLIT),
// B: [cb][kbgA][128][8] (+lo). K fully pre-padded: nsteps = kbgA/4.
// OMODE 0: f32 row-major out (guard c<N). OMODE 1: bf16 tiled out.
// OMODE 2: split bf16 tiled out (hi+lo). Tiled outputs zero the col-pad.
// ACT: 0 none, 1 relu, 2 leaky(0.1), 3 tanh
// ---------------------------------------------------------------------------
template<int ACT, bool SPLIT, int OMODE>
__global__ __launch_bounds__(256)
void gemm_mfma(const ushort* __restrict__ At, const ushort* __restrict__ Alt,
               const ushort* __restrict__ Bt, const ushort* __restrict__ Blt,
               const float* __restrict__ bias,
               float* __restrict__ Cf, ushort* __restrict__ Chi, ushort* __restrict__ Clo,
               int kbgA, int nsteps, int N)
{
    __shared__ short8v AhV[512];                       // 8192 B
    __shared__ short8v BhV[512];
    __shared__ short8v AlV[SPLIT ? 512 : 1];
    __shared__ short8v BlV[SPLIT ? 512 : 1];
    ushort* Ah = (ushort*)AhV;
    ushort* Bh = (ushort*)BhV;
    ushort* Al = (ushort*)AlV;
    ushort* Bl = (ushort*)BlV;

    const int tid  = threadIdx.x;
    const int lane = tid & 63;
    const int wid  = tid >> 6;
    const int wr   = (wid >> 1) * 64;
    const int wc   = (wid & 1) * 64;

    // XCD-aware bijective swizzle (nwg % 8 == 0 always: gridDim.y == 128)
    const int flat = blockIdx.y * gridDim.x + blockIdx.x;
    const int cpx  = (gridDim.x * gridDim.y) >> 3;
    const int swz  = (flat & 7) * cpx + (flat >> 3);
    const int cb   = swz % gridDim.x;
    const int rb   = swz / gridDim.x;
    const int row0 = rb * 128;
    const int col0 = cb * 128;

    f32x4 acc[4][4];
#pragma unroll
    for (int m = 0; m < 4; ++m)
#pragma unroll
        for (int n = 0; n < 4; ++n) acc[m][n] = (f32x4){0.f, 0.f, 0.f, 0.f};

    const int fr = lane & 15;
    const int kq = lane >> 4;

    const size_t abase = (size_t)rb * kbgA * 1024;
    const size_t bbase = (size_t)cb * kbgA * 1024;

    for (int s = 0; s < nsteps; ++s) {
        const size_t off = (size_t)s * 4096;
        stage_tile(At + abase + off, Ah, wid, lane);
        stage_tile(Bt + bbase + off, Bh, wid, lane);
        if (SPLIT) {
            stage_tile(Alt + abase + off, Al, wid, lane);
            stage_tile(Blt + bbase + off, Bl, wid, lane);
        }
        __syncthreads();   // compiler drains vmcnt(0) here (m97 structure)

        short8v a_h[4], b_h[4], a_l[4], b_l[4];
#pragma unroll
        for (int m = 0; m < 4; ++m) {
            a_h[m] = *(const short8v*)&Ah[kq * 1024 + (wr + m * 16 + fr) * 8];
            if (SPLIT) a_l[m] = *(const short8v*)&Al[kq * 1024 + (wr + m * 16 + fr) * 8];
        }
#pragma unroll
        for (int n = 0; n < 4; ++n) {
            b_h[n] = *(const short8v*)&Bh[kq * 1024 + (wc + n * 16 + fr) * 8];
            if (SPLIT) b_l[n] = *(const short8v*)&Bl[kq * 1024 + (wc + n * 16 + fr) * 8];
        }
#pragma unroll
        for (int m = 0; m < 4; ++m)
#pragma unroll
            for (int n = 0; n < 4; ++n) {
                acc[m][n] = __builtin_amdgcn_mfma_f32_16x16x32_bf16(a_h[m], b_h[n], acc[m][n], 0, 0, 0);
                if (SPLIT) {
                    acc[m][n] = __builtin_amdgcn_mfma_f32_16x16x32_bf16(a_h[m], b_l[n], acc[m][n], 0, 0, 0);
                    acc[m][n] = __builtin_amdgcn_mfma_f32_16x16x32_bf16(a_l[m], b_h[n], acc[m][n], 0, 0, 0);
                }
            }
        __syncthreads();
    }

    // epilogue: C/D layout col=lane&15, row=(lane>>4)*4+reg
    const int kbgN = gridDim.x << 4;   // output tiled kbg (Npad/8)
#pragma unroll
    for (int n = 0; n < 4; ++n) {
        const int c = col0 + wc + n * 16 + fr;
        const float bv = (bias && c < N) ? bias[c] : 0.f;
#pragma unroll
        for (int m = 0; m < 4; ++m) {
#pragma unroll
            for (int i = 0; i < 4; ++i) {
                const int r = row0 + wr + m * 16 + kq * 4 + i;
                float v = acc[m][n][i] + bv;
                if (ACT == 1) v = fmaxf(v, 0.f);
                else if (ACT == 2) v = (v > 0.f) ? v : 0.1f * v;
                else if (ACT == 3) v = tanhf(v);
                if (OMODE == 0) {
                    if (c < N) Cf[(size_t)r * N + c] = v;
                } else {
                    if (c >= N) v = 0.f;   // zero the col-pad region
                    const size_t oi = (((size_t)(r >> 7) * kbgN + (c >> 3)) * 128 + (r & 127)) * 8 + (c & 7);
                    const ushort h = f2bf(v);
                    Chi[oi] = h;
                    if (OMODE == 2) Clo[oi] = f2bf(v - bf2f(h));
                }
            }
        }
    }
}

// ---------------------------------------------------------------------------
// f32 VALU GEMM for S = Zenc @ E^T (argmin needs f32 fidelity; ~1 GF)
// ---------------------------------------------------------------------------
__global__ __launch_bounds__(256)
void gemm_f32_bt(const float* __restrict__ A, const float* __restrict__ W,
                 float* __restrict__ C, int M, int K, int N)
{
    __shared__ float As[16][68];
    __shared__ float Ws[16][68];

    const int tid = threadIdx.x;
    const int tx = tid & 15, ty = tid >> 4;
    const int row0 = blockIdx.y * 64, col0 = blockIdx.x * 64;

    float acc[4][4];
#pragma unroll
    for (int i = 0; i < 4; ++i)
#pragma unroll
        for (int j = 0; j < 4; ++j) acc[i][j] = 0.f;

    const int a_row = tid >> 2, a_k4 = (tid & 3) << 2;
    const int t_col = tid >> 2, t_k4 = (tid & 3) << 2;

    for (int k0 = 0; k0 < K; k0 += 16) {
        {
            const int gr = row0 + a_row, gk = k0 + a_k4;
            float4 av = *reinterpret_cast<const float4*>(A + (size_t)gr * K + gk);
            As[a_k4 + 0][a_row] = av.x; As[a_k4 + 1][a_row] = av.y;
            As[a_k4 + 2][a_row] = av.z; As[a_k4 + 3][a_row] = av.w;
        }
        {
            const int gc = col0 + t_col, gk = k0 + t_k4;
            float4 wv = *reinterpret_cast<const float4*>(W + (size_t)gc * K + gk);
            Ws[t_k4 + 0][t_col] = wv.x; Ws[t_k4 + 1][t_col] = wv.y;
            Ws[t_k4 + 2][t_col] = wv.z; Ws[t_k4 + 3][t_col] = wv.w;
        }
        __syncthreads();
#pragma unroll
        for (int kk = 0; kk < 16; ++kk) {
            float4 a = *reinterpret_cast<const float4*>(&As[kk][ty << 2]);
            float4 w = *reinterpret_cast<const float4*>(&Ws[kk][tx << 2]);
            acc[0][0] += a.x * w.x; acc[0][1] += a.x * w.y; acc[0][2] += a.x * w.z; acc[0][3] += a.x * w.w;
            acc[1][0] += a.y * w.x; acc[1][1] += a.y * w.y; acc[1][2] += a.y * w.z; acc[1][3] += a.y * w.w;
            acc[2][0] += a.z * w.x; acc[2][1] += a.z * w.y; acc[2][2] += a.z * w.z; acc[2][3] += a.z * w.w;
            acc[3][0] += a.w * w.x; acc[3][1] += a.w * w.y; acc[3][2] += a.w * w.z; acc[3][3] += a.w * w.w;
        }
        __syncthreads();
    }
#pragma unroll
    for (int i = 0; i < 4; ++i) {
        const int r = row0 + (ty << 2) + i;
#pragma unroll
        for (int j = 0; j < 4; ++j) {
            const int c = col0 + (tx << 2) + j;
            C[(size_t)r * N + c] = acc[i][j];
        }
    }
}

__global__ void row_norms64(const float* __restrict__ X, float* __restrict__ out, int rows)
{
    int r = blockIdx.x * blockDim.x + threadIdx.x;
    if (r >= rows) return;
    const float* p = X + (size_t)r * 64;
    float s = 0.f;
#pragma unroll
    for (int i = 0; i < 16; ++i) {
        float4 v = *reinterpret_cast<const float4*>(p + i * 4);
        s += v.x * v.x + v.y * v.y + v.z * v.z + v.w * v.w;
    }
    out[r] = s;
}

// row argmin over 512 codebook entries; gather E row -> Zdec (f32) and
// tiled-bf16 Zdcb (kbg=8) for the decoder's first MFMA GEMM.
__global__ __launch_bounds__(256)
void argmin_rows(const float* __restrict__ S, const float* __restrict__ En2,
                 const float* __restrict__ E, float* __restrict__ Zdec,
                 ushort* __restrict__ Zdcb)
{
    const int wave = (blockIdx.x * blockDim.x + threadIdx.x) >> 6;
    const int lane = threadIdx.x & 63;
    if (wave >= 16384) return;
    const float* Srow = S + (size_t)wave * 512;
    float best = INFINITY;
    int bidx = 0x7fffffff;
    for (int k = lane; k < 512; k += 64) {
        float v = En2[k] - 2.0f * Srow[k];
        if (v < best) { best = v; bidx = k; }
    }
#pragma unroll
    for (int off = 32; off > 0; off >>= 1) {
        float ov = __shfl_down(best, off);
        int   oi = __shfl_down(bidx, off);
        if (ov < best || (ov == best && oi < bidx)) { best = ov; bidx = oi; }
    }
    bidx = __shfl(bidx, 0);
    const float val = E[(size_t)bidx * 64 + lane];
    Zdec[(size_t)wave * 64 + lane] = val;
    const size_t oi = (((size_t)(wave >> 7) * 8 + (lane >> 3)) * 128 + (wave & 127)) * 8 + (lane & 7);
    Zdcb[oi] = f2bf(val);
}

// column argmin: 32 blocks x 16 columns each; 16 lanes cover one 64B line of S.
__global__ __launch_bounds__(256)
void argmin_cols16(const float* __restrict__ S, const float* __restrict__ Zn2,
                   const float* __restrict__ Zenc, float* __restrict__ Zemb)
{
    const int tid = threadIdx.x;
    const int c  = tid & 15;           // column within group
    const int br = tid >> 4;           // 16 row-streams
    const int k  = blockIdx.x * 16 + c;
    float best = INFINITY;
    int bidx = 0x7fffffff;
    for (int b = br; b < 16384; b += 16) {
        float v = Zn2[b] - 2.0f * S[(size_t)b * 512 + k];
        if (v < best) { best = v; bidx = b; }   // ascending b: first-min kept
    }
    __shared__ float vs[16][16];
    __shared__ int   is_[16][16];
    __shared__ int   bestIdx[16];
    vs[br][c] = best; is_[br][c] = bidx;
    __syncthreads();
    if (tid < 16) {
        float bv = vs[0][tid]; int bi = is_[0][tid];
#pragma unroll
        for (int t = 1; t < 16; ++t) {
            const float v = vs[t][tid];
            const int  ii = is_[t][tid];
            if (v < bv || (v == bv && ii < bi)) { bv = v; bi = ii; }
        }
        bestIdx[tid] = bi;
    }
    __syncthreads();
#pragma unroll
    for (int p = 0; p < 4; ++p) {
        const int cc = (p << 2) + (tid >> 6);
        const int d  = tid & 63;
        Zemb[((size_t)blockIdx.x * 16 + cc) * 64 + d] = Zenc[(size_t)bestIdx[cc] * 64 + d];
    }
}

// X [16384][784] f32 -> tiled split bf16 [128 rb][100 kbg][128][8], k-pad zero
__global__ void conv_x(const float* __restrict__ X, ushort* __restrict__ hi,
                       ushort* __restrict__ lo)
{
    const long total = 128L * 100 * 1024;
    for (long idx = blockIdx.x * 256L + threadIdx.x; idx < total; idx += (long)gridDim.x * 256L) {
        const int j  = (int)(idx & 7);
        const long t = idx >> 3;
        const int rn = (int)(t & 127);
        const long u = t >> 7;
        const int kb = (int)(u % 100);
        const int rb = (int)(u / 100);
        const int r = rb * 128 + rn;
        const int k = kb * 8 + j;
        const float v = (k < 784) ? X[(size_t)r * 784 + k] : 0.f;
        const ushort h = f2bf(v);
        hi[idx] = h;
        lo[idx] = f2bf(v - bf2f(h));
    }
}

// W [K][N] f32 -> tiled bf16 [npanels][kbgTot][128][8], zero-padded both dims
template<bool SPLIT>
__global__ void prep_w(const float* __restrict__ W, ushort* __restrict__ hi,
                       ushort* __restrict__ lo, int K, int N, int kbgTot, int npanels)
{
    const long total = (long)npanels * kbgTot * 1024;
    for (long idx = blockIdx.x * 256L + threadIdx.x; idx < total; idx += (long)gridDim.x * 256L) {
        const int j  = (int)(idx & 7);
        const long t = idx >> 3;
        const int cn = (int)(t & 127);
        const long u = t >> 7;
        const int kb = (int)(u % kbgTot);
        const int p  = (int)(u / kbgTot);
        const int k = kb * 8 + j;
        const int n = p * 128 + cn;
        const float v = (k < K && n < N) ? W[(size_t)k * N + n] : 0.f;
        const ushort h = f2bf(v);
        hi[idx] = h;
        if (SPLIT) lo[idx] = f2bf(v - bf2f(h));
    }
}

extern "C" void kernel_launch(void* const* d_in, const int* in_sizes, int n_in,
                              void* d_out, int out_size, void* d_ws, size_t ws_size,
                              hipStream_t stream)
{
    const float* X  = (const float*)d_in[0];
    const float* W1 = (const float*)d_in[1];
    const float* b1 = (const float*)d_in[2];
    const float* W2 = (const float*)d_in[3];
    const float* b2 = (const float*)d_in[4];
    const float* W3 = (const float*)d_in[5];
    const float* b3 = (const float*)d_in[6];
    const float* W4 = (const float*)d_in[7];
    const float* b4 = (const float*)d_in[8];
    const float* E  = (const float*)d_in[9];
    const float* V1 = (const float*)d_in[10];
    const float* c1 = (const float*)d_in[11];
    const float* V2 = (const float*)d_in[12];
    const float* c2 = (const float*)d_in[13];
    const float* V3 = (const float*)d_in[14];
    const float* c3 = (const float*)d_in[15];
    const float* V4 = (const float*)d_in[16];
    const float* c4 = (const float*)d_in[17];

    float* out  = (float*)d_out;
    float* Xrec = out;                  // 16384*784  (bytes [0, 51,380,224))
    float* Zenc = out + 12845056;       // 16384*64
    float* Zdec = out + 13893632;       // 16384*64
    float* Zemb = out + 14942208;       // 512*64

    // ---- workspace layout (peak 97.8 MB; proven budget >= 118.0 MB) ----
    char* ws = (char*)d_ws;
    // [0, 52.4M): Xhi/Xlo -> h2h/h2l -> S -> g3
    ushort* Xhi = (ushort*)(ws + 0);           // 26,214,400
    ushort* Xlo = (ushort*)(ws + 26214400);    // -> 52,428,800
    ushort* h2h = (ushort*)(ws + 0);           // 16,777,216 (after enc1)
    ushort* h2l = (ushort*)(ws + 16777216);    // -> 33,554,432
    float*  S   = (float*)(ws + 0);            // 33,554,432 (after enc3)
    ushort* g3  = (ushort*)(ws + 0);           // 33,554,432 (after argmins)
    // [52.4M, 86.0M): h1l -> h3h/h3l -> g1/g2
    ushort* h1l = (ushort*)(ws + 52428800);    // 33,554,432
    ushort* h3h = (ushort*)(ws + 52428800);    // 12,582,912 (after enc2)
    ushort* h3l = (ushort*)(ws + 65011712);    // -> 77,594,624
    ushort* g1  = (ushort*)(ws + 52428800);    // 12,582,912 (after enc4)
    ushort* g2  = (ushort*)(ws + 65011712);    // 16,777,216 -> 81,788,928
    // h1h parks in d_out's Xrec slab (dead before dec4)
    ushort* h1h = (ushort*)d_out;              // 33,554,432 < 51,380,224
    // persistent tail
    float*  Zn2  = (float*)(ws + 85983232);
    float*  En2  = (float*)(ws + 86048768);
    ushort* Zdcb = (ushort*)(ws + 86050816);   // 2,097,152
    ushort* Wt1h = (ushort*)(ws + 88147968);   // 8p x 100kbg: 1,638,400
    ushort* Wt1l = (ushort*)(ws + 89786368);
    ushort* Wt2h = (ushort*)(ws + 91424768);   // 4p x 128: 1,048,576
    ushort* Wt2l = (ushort*)(ws + 92473344);
    ushort* Wt3h = (ushort*)(ws + 93521920);   // 3p x 64: 393,216
    ushort* Wt3l = (ushort*)(ws + 93915136);
    ushort* Wt4h = (ushort*)(ws + 94308352);   // 1p x 48: 98,304
    ushort* Wt4l = (ushort*)(ws + 94406656);
    ushort* Vt1  = (ushort*)(ws + 94504960);   // 3p x 8: 49,152
    ushort* Vt2  = (ushort*)(ws + 94554112);   // 4p x 48: 393,216
    ushort* Vt3  = (ushort*)(ws + 94947328);   // 8p x 64: 1,048,576
    ushort* Vt4  = (ushort*)(ws + 95995904);   // 7p x 128: 1,835,008 -> 97,830,912

    const dim3 blk(256);

    // ---- conversion & tiling ----
    conv_x<<<dim3(2048), blk, 0, stream>>>(X, Xhi, Xlo);
    prep_w<true ><<<dim3(256), blk, 0, stream>>>(W1, Wt1h, Wt1l, 784, 1000, 100, 8);
    prep_w<true ><<<dim3(256), blk, 0, stream>>>(W2, Wt2h, Wt2l, 1000, 500, 128, 4);
    prep_w<true ><<<dim3(128), blk, 0, stream>>>(W3, Wt3h, Wt3l, 500, 300, 64, 3);
    prep_w<true ><<<dim3(64),  blk, 0, stream>>>(W4, Wt4h, Wt4l, 300, 64, 48, 1);
    prep_w<false><<<dim3(64),  blk, 0, stream>>>(V1, Vt1, nullptr, 64, 300, 8, 3);
    prep_w<false><<<dim3(128), blk, 0, stream>>>(V2, Vt2, nullptr, 300, 500, 48, 4);
    prep_w<false><<<dim3(256), blk, 0, stream>>>(V3, Vt3, nullptr, 500, 1000, 64, 8);
    prep_w<false><<<dim3(256), blk, 0, stream>>>(V4, Vt4, nullptr, 1000, 784, 128, 7);

    // ---- encoder: split-bf16 (3-MFMA) ----
    gemm_mfma<1, true, 2><<<dim3(8, 128), blk, 0, stream>>>(Xhi, Xlo, Wt1h, Wt1l, b1, nullptr, h1h, h1l, 100, 25, 1000);
    gemm_mfma<1, true, 2><<<dim3(4, 128), blk, 0, stream>>>(h1h, h1l, Wt2h, Wt2l, b2, nullptr, h2h, h2l, 128, 32, 500);
    gemm_mfma<1, true, 2><<<dim3(3, 128), blk, 0, stream>>>(h2h, h2l, Wt3h, Wt3l, b3, nullptr, h3h, h3l, 64, 16, 300);
    gemm_mfma<0, true, 0><<<dim3(1, 128), blk, 0, stream>>>(h3h, h3l, Wt4h, Wt4l, b4, Zenc, nullptr, nullptr, 48, 12, 64);

    // ---- nearest-neighbor (f32) ----
    row_norms64<<<dim3(8),  dim3(64), 0, stream>>>(E,    En2, 512);
    row_norms64<<<dim3(64), blk,      0, stream>>>(Zenc, Zn2, 16384);
    gemm_f32_bt<<<dim3(8, 256), blk, 0, stream>>>(Zenc, E, S, 16384, 64, 512);
    argmin_rows<<<dim3(4096), blk, 0, stream>>>(S, En2, E, Zdec, Zdcb);
    argmin_cols16<<<dim3(32), blk, 0, stream>>>(S, Zn2, Zenc, Zemb);

    // ---- decoder: plain bf16 MFMA ----
    gemm_mfma<2, false, 1><<<dim3(3, 128), blk, 0, stream>>>(Zdcb, nullptr, Vt1, nullptr, c1, nullptr, g1, nullptr, 8, 2, 300);
    gemm_mfma<2, false, 1><<<dim3(4, 128), blk, 0, stream>>>(g1, nullptr, Vt2, nullptr, c2, nullptr, g2, nullptr, 48, 12, 500);
    gemm_mfma<2, false, 1><<<dim3(8, 128), blk, 0, stream>>>(g2, nullptr, Vt3, nullptr, c3, nullptr, g3, nullptr, 64, 16, 1000);
    gemm_mfma<3, false, 0><<<dim3(7, 128), blk, 0, stream>>>(g3, nullptr, Vt4, nullptr, c4, Xrec, nullptr, nullptr, 128, 32, 784);
}

// Round 6
// 569.115 us; speedup vs baseline: 1.4967x; 1.4967x over previous
//
#include <hip/hip_runtime.h>
#include <hip/hip_bf16.h>

// ---------------------------------------------------------------------------
// VQ-VAE forward. All GEMM operands pre-tiled to MFMA-ready layout
// [panel][kbg][128][8] (panel = 128 rows/cols, kbg = 8 k's), staged via
// global_load_lds dwordx4. Encoder split-bf16 (3-MFMA), decoder plain bf16.
// Round 6: identical resubmit of round 5 (infra failure, no kernel verdict).
// ---------------------------------------------------------------------------

typedef __attribute__((ext_vector_type(8))) short short8v;
typedef __attribute__((ext_vector_type(4))) float f32x4;

__device__ inline ushort f2bf(float v) {
    __hip_bfloat16 h = __float2bfloat16(v);
    return *reinterpret_cast<ushort*>(&h);
}
__device__ inline float bf2f(ushort s) {
    __hip_bfloat16 h;
    *reinterpret_cast<ushort*>(&h) = s;
    return __bfloat162float(h);
}

// copy 8192 B (one K-step tile: 4 kb-blocks of [128][8] bf16) global -> LDS.
// Layouts are identical, so this is a pure linear DMA: 8 chunks of 1024 B,
// 4 waves x 2 issues, lane l writes lds chunk_base + l*16.
__device__ __forceinline__ void stage_tile(const ushort* __restrict__ src,
                                           ushort* dst, int wid, int lane)
{
#pragma unroll
    for (int j = 0; j < 2; ++j) {
        const int ci = (j << 2) + wid;
        __builtin_amdgcn_global_load_lds(
            (const __attribute__((address_space(1))) unsigned int*)(src + ci * 512 + lane * 8),
            (__attribute__((address_space(3))) unsigned int*)(dst + ci * 512),
            16, 0, 0);
    }
}

// ---------------------------------------------------------------------------
// MFMA GEMM on tiled operands. A: [rb][kbgA][128][8] (+lo if SPLIT),
// B: [cb][kbgA][128][8] (+lo). K fully pre-padded: nsteps = kbgA/4.
// OMODE 0: f32 row-major out (guard c<N). OMODE 1: bf16 tiled out.
// OMODE 2: split bf16 tiled out (hi+lo). Tiled outputs zero the col-pad.
// ACT: 0 none, 1 relu, 2 leaky(0.1), 3 tanh
// ---------------------------------------------------------------------------
template<int ACT, bool SPLIT, int OMODE>
__global__ __launch_bounds__(256)
void gemm_mfma(const ushort* __restrict__ At, const ushort* __restrict__ Alt,
               const ushort* __restrict__ Bt, const ushort* __restrict__ Blt,
               const float* __restrict__ bias,
               float* __restrict__ Cf, ushort* __restrict__ Chi, ushort* __restrict__ Clo,
               int kbgA, int nsteps, int N)
{
    __shared__ short8v AhV[512];                       // 8192 B
    __shared__ short8v BhV[512];
    __shared__ short8v AlV[SPLIT ? 512 : 1];
    __shared__ short8v BlV[SPLIT ? 512 : 1];
    ushort* Ah = (ushort*)AhV;
    ushort* Bh = (ushort*)BhV;
    ushort* Al = (ushort*)AlV;
    ushort* Bl = (ushort*)BlV;

    const int tid  = threadIdx.x;
    const int lane = tid & 63;
    const int wid  = tid >> 6;
    const int wr   = (wid >> 1) * 64;
    const int wc   = (wid & 1) * 64;

    // XCD-aware bijective swizzle (nwg % 8 == 0 always: gridDim.y == 128)
    const int flat = blockIdx.y * gridDim.x + blockIdx.x;
    const int cpx  = (gridDim.x * gridDim.y) >> 3;
    const int swz  = (flat & 7) * cpx + (flat >> 3);
    const int cb   = swz % gridDim.x;
    const int rb   = swz / gridDim.x;
    const int row0 = rb * 128;
    const int col0 = cb * 128;

    f32x4 acc[4][4];
#pragma unroll
    for (int m = 0; m < 4; ++m)
#pragma unroll
        for (int n = 0; n < 4; ++n) acc[m][n] = (f32x4){0.f, 0.f, 0.f, 0.f};

    const int fr = lane & 15;
    const int kq = lane >> 4;

    const size_t abase = (size_t)rb * kbgA * 1024;
    const size_t bbase = (size_t)cb * kbgA * 1024;

    for (int s = 0; s < nsteps; ++s) {
        const size_t off = (size_t)s * 4096;
        stage_tile(At + abase + off, Ah, wid, lane);
        stage_tile(Bt + bbase + off, Bh, wid, lane);
        if (SPLIT) {
            stage_tile(Alt + abase + off, Al, wid, lane);
            stage_tile(Blt + bbase + off, Bl, wid, lane);
        }
        __syncthreads();   // compiler drains vmcnt(0) here (m97 structure)

        short8v a_h[4], b_h[4], a_l[4], b_l[4];
#pragma unroll
        for (int m = 0; m < 4; ++m) {
            a_h[m] = *(const short8v*)&Ah[kq * 1024 + (wr + m * 16 + fr) * 8];
            if (SPLIT) a_l[m] = *(const short8v*)&Al[kq * 1024 + (wr + m * 16 + fr) * 8];
        }
#pragma unroll
        for (int n = 0; n < 4; ++n) {
            b_h[n] = *(const short8v*)&Bh[kq * 1024 + (wc + n * 16 + fr) * 8];
            if (SPLIT) b_l[n] = *(const short8v*)&Bl[kq * 1024 + (wc + n * 16 + fr) * 8];
        }
#pragma unroll
        for (int m = 0; m < 4; ++m)
#pragma unroll
            for (int n = 0; n < 4; ++n) {
                acc[m][n] = __builtin_amdgcn_mfma_f32_16x16x32_bf16(a_h[m], b_h[n], acc[m][n], 0, 0, 0);
                if (SPLIT) {
                    acc[m][n] = __builtin_amdgcn_mfma_f32_16x16x32_bf16(a_h[m], b_l[n], acc[m][n], 0, 0, 0);
                    acc[m][n] = __builtin_amdgcn_mfma_f32_16x16x32_bf16(a_l[m], b_h[n], acc[m][n], 0, 0, 0);
                }
            }
        __syncthreads();
    }

    // epilogue: C/D layout col=lane&15, row=(lane>>4)*4+reg
    const int kbgN = gridDim.x << 4;   // output tiled kbg (Npad/8)
#pragma unroll
    for (int n = 0; n < 4; ++n) {
        const int c = col0 + wc + n * 16 + fr;
        const float bv = (bias && c < N) ? bias[c] : 0.f;
#pragma unroll
        for (int m = 0; m < 4; ++m) {
#pragma unroll
            for (int i = 0; i < 4; ++i) {
                const int r = row0 + wr + m * 16 + kq * 4 + i;
                float v = acc[m][n][i] + bv;
                if (ACT == 1) v = fmaxf(v, 0.f);
                else if (ACT == 2) v = (v > 0.f) ? v : 0.1f * v;
                else if (ACT == 3) v = tanhf(v);
                if (OMODE == 0) {
                    if (c < N) Cf[(size_t)r * N + c] = v;
                } else {
                    if (c >= N) v = 0.f;   // zero the col-pad region
                    const size_t oi = (((size_t)(r >> 7) * kbgN + (c >> 3)) * 128 + (r & 127)) * 8 + (c & 7);
                    const ushort h = f2bf(v);
                    Chi[oi] = h;
                    if (OMODE == 2) Clo[oi] = f2bf(v - bf2f(h));
                }
            }
        }
    }
}

// ---------------------------------------------------------------------------
// f32 VALU GEMM for S = Zenc @ E^T (argmin needs f32 fidelity; ~1 GF)
// ---------------------------------------------------------------------------
__global__ __launch_bounds__(256)
void gemm_f32_bt(const float* __restrict__ A, const float* __restrict__ W,
                 float* __restrict__ C, int M, int K, int N)
{
    __shared__ float As[16][68];
    __shared__ float Ws[16][68];

    const int tid = threadIdx.x;
    const int tx = tid & 15, ty = tid >> 4;
    const int row0 = blockIdx.y * 64, col0 = blockIdx.x * 64;

    float acc[4][4];
#pragma unroll
    for (int i = 0; i < 4; ++i)
#pragma unroll
        for (int j = 0; j < 4; ++j) acc[i][j] = 0.f;

    const int a_row = tid >> 2, a_k4 = (tid & 3) << 2;
    const int t_col = tid >> 2, t_k4 = (tid & 3) << 2;

    for (int k0 = 0; k0 < K; k0 += 16) {
        {
            const int gr = row0 + a_row, gk = k0 + a_k4;
            float4 av = *reinterpret_cast<const float4*>(A + (size_t)gr * K + gk);
            As[a_k4 + 0][a_row] = av.x; As[a_k4 + 1][a_row] = av.y;
            As[a_k4 + 2][a_row] = av.z; As[a_k4 + 3][a_row] = av.w;
        }
        {
            const int gc = col0 + t_col, gk = k0 + t_k4;
            float4 wv = *reinterpret_cast<const float4*>(W + (size_t)gc * K + gk);
            Ws[t_k4 + 0][t_col] = wv.x; Ws[t_k4 + 1][t_col] = wv.y;
            Ws[t_k4 + 2][t_col] = wv.z; Ws[t_k4 + 3][t_col] = wv.w;
        }
        __syncthreads();
#pragma unroll
        for (int kk = 0; kk < 16; ++kk) {
            float4 a = *reinterpret_cast<const float4*>(&As[kk][ty << 2]);
            float4 w = *reinterpret_cast<const float4*>(&Ws[kk][tx << 2]);
            acc[0][0] += a.x * w.x; acc[0][1] += a.x * w.y; acc[0][2] += a.x * w.z; acc[0][3] += a.x * w.w;
            acc[1][0] += a.y * w.x; acc[1][1] += a.y * w.y; acc[1][2] += a.y * w.z; acc[1][3] += a.y * w.w;
            acc[2][0] += a.z * w.x; acc[2][1] += a.z * w.y; acc[2][2] += a.z * w.z; acc[2][3] += a.z * w.w;
            acc[3][0] += a.w * w.x; acc[3][1] += a.w * w.y; acc[3][2] += a.w * w.z; acc[3][3] += a.w * w.w;
        }
        __syncthreads();
    }
#pragma unroll
    for (int i = 0; i < 4; ++i) {
        const int r = row0 + (ty << 2) + i;
#pragma unroll
        for (int j = 0; j < 4; ++j) {
            const int c = col0 + (tx << 2) + j;
            C[(size_t)r * N + c] = acc[i][j];
        }
    }
}

__global__ void row_norms64(const float* __restrict__ X, float* __restrict__ out, int rows)
{
    int r = blockIdx.x * blockDim.x + threadIdx.x;
    if (r >= rows) return;
    const float* p = X + (size_t)r * 64;
    float s = 0.f;
#pragma unroll
    for (int i = 0; i < 16; ++i) {
        float4 v = *reinterpret_cast<const float4*>(p + i * 4);
        s += v.x * v.x + v.y * v.y + v.z * v.z + v.w * v.w;
    }
    out[r] = s;
}

// row argmin over 512 codebook entries; gather E row -> Zdec (f32) and
// tiled-bf16 Zdcb (kbg=8) for the decoder's first MFMA GEMM.
__global__ __launch_bounds__(256)
void argmin_rows(const float* __restrict__ S, const float* __restrict__ En2,
                 const float* __restrict__ E, float* __restrict__ Zdec,
                 ushort* __restrict__ Zdcb)
{
    const int wave = (blockIdx.x * blockDim.x + threadIdx.x) >> 6;
    const int lane = threadIdx.x & 63;
    if (wave >= 16384) return;
    const float* Srow = S + (size_t)wave * 512;
    float best = INFINITY;
    int bidx = 0x7fffffff;
    for (int k = lane; k < 512; k += 64) {
        float v = En2[k] - 2.0f * Srow[k];
        if (v < best) { best = v; bidx = k; }
    }
#pragma unroll
    for (int off = 32; off > 0; off >>= 1) {
        float ov = __shfl_down(best, off);
        int   oi = __shfl_down(bidx, off);
        if (ov < best || (ov == best && oi < bidx)) { best = ov; bidx = oi; }
    }
    bidx = __shfl(bidx, 0);
    const float val = E[(size_t)bidx * 64 + lane];
    Zdec[(size_t)wave * 64 + lane] = val;
    const size_t oi = (((size_t)(wave >> 7) * 8 + (lane >> 3)) * 128 + (wave & 127)) * 8 + (lane & 7);
    Zdcb[oi] = f2bf(val);
}

// ---------------------------------------------------------------------------
// column argmin, two-phase.
// Phase 1: 256 blocks; block g scans rows [64g, 64g+64). Thread tid tracks
// columns tid and tid+256 (coalesced row reads). Partials -> [col][g].
// Phase 2: 512 blocks (one per column); coalesced partial reduce + gather.
// Lexicographic (val, idx) everywhere => matches jnp.argmin first-min.
// ---------------------------------------------------------------------------
__global__ __launch_bounds__(256)
void argmin_cols_p1(const float* __restrict__ S, const float* __restrict__ Zn2,
                    float* __restrict__ pval, int* __restrict__ pidx)
{
    const int g   = blockIdx.x;
    const int tid = threadIdx.x;
    const int r0  = g << 6;
    float b0 = INFINITY, b1 = INFINITY;
    int   i0 = 0, i1 = 0;
    for (int r = 0; r < 64; ++r) {
        const float zn = Zn2[r0 + r];
        const float* row = S + (size_t)(r0 + r) * 512;
        const float v0 = zn - 2.0f * row[tid];
        const float v1 = zn - 2.0f * row[tid + 256];
        if (v0 < b0) { b0 = v0; i0 = r0 + r; }   // ascending r: first-min kept
        if (v1 < b1) { b1 = v1; i1 = r0 + r; }
    }
    pval[(size_t)tid * 256 + g]         = b0;
    pidx[(size_t)tid * 256 + g]         = i0;
    pval[(size_t)(tid + 256) * 256 + g] = b1;
    pidx[(size_t)(tid + 256) * 256 + g] = i1;
}

__global__ __launch_bounds__(256)
void argmin_cols_p2(const float* __restrict__ pval, const int* __restrict__ pidx,
                    const float* __restrict__ Zenc, float* __restrict__ Zemb)
{
    const int k   = blockIdx.x;
    const int tid = threadIdx.x;
    float v = pval[(size_t)k * 256 + tid];
    int   i = pidx[(size_t)k * 256 + tid];
    __shared__ float vs[256];
    __shared__ int   is_[256];
    vs[tid] = v; is_[tid] = i;
    __syncthreads();
    for (int s = 128; s > 0; s >>= 1) {
        if (tid < s) {
            if (vs[tid + s] < vs[tid] ||
                (vs[tid + s] == vs[tid] && is_[tid + s] < is_[tid])) {
                vs[tid] = vs[tid + s]; is_[tid] = is_[tid + s];
            }
        }
        __syncthreads();
    }
    const int idx = is_[0];
    if (tid < 64) Zemb[(size_t)k * 64 + tid] = Zenc[(size_t)idx * 64 + tid];
}

// X [16384][784] f32 -> tiled split bf16 [128 rb][100 kbg][128][8], k-pad zero
__global__ void conv_x(const float* __restrict__ X, ushort* __restrict__ hi,
                       ushort* __restrict__ lo)
{
    const long total = 128L * 100 * 1024;
    for (long idx = blockIdx.x * 256L + threadIdx.x; idx < total; idx += (long)gridDim.x * 256L) {
        const int j  = (int)(idx & 7);
        const long t = idx >> 3;
        const int rn = (int)(t & 127);
        const long u = t >> 7;
        const int kb = (int)(u % 100);
        const int rb = (int)(u / 100);
        const int r = rb * 128 + rn;
        const int k = kb * 8 + j;
        const float v = (k < 784) ? X[(size_t)r * 784 + k] : 0.f;
        const ushort h = f2bf(v);
        hi[idx] = h;
        lo[idx] = f2bf(v - bf2f(h));
    }
}

// W [K][N] f32 -> tiled bf16 [npanels][kbgTot][128][8], zero-padded both dims
template<bool SPLIT>
__global__ void prep_w(const float* __restrict__ W, ushort* __restrict__ hi,
                       ushort* __restrict__ lo, int K, int N, int kbgTot, int npanels)
{
    const long total = (long)npanels * kbgTot * 1024;
    for (long idx = blockIdx.x * 256L + threadIdx.x; idx < total; idx += (long)gridDim.x * 256L) {
        const int j  = (int)(idx & 7);
        const long t = idx >> 3;
        const int cn = (int)(t & 127);
        const long u = t >> 7;
        const int kb = (int)(u % kbgTot);
        const int p  = (int)(u / kbgTot);
        const int k = kb * 8 + j;
        const int n = p * 128 + cn;
        const float v = (k < K && n < N) ? W[(size_t)k * N + n] : 0.f;
        const ushort h = f2bf(v);
        hi[idx] = h;
        if (SPLIT) lo[idx] = f2bf(v - bf2f(h));
    }
}

extern "C" void kernel_launch(void* const* d_in, const int* in_sizes, int n_in,
                              void* d_out, int out_size, void* d_ws, size_t ws_size,
                              hipStream_t stream)
{
    const float* X  = (const float*)d_in[0];
    const float* W1 = (const float*)d_in[1];
    const float* b1 = (const float*)d_in[2];
    const float* W2 = (const float*)d_in[3];
    const float* b2 = (const float*)d_in[4];
    const float* W3 = (const float*)d_in[5];
    const float* b3 = (const float*)d_in[6];
    const float* W4 = (const float*)d_in[7];
    const float* b4 = (const float*)d_in[8];
    const float* E  = (const float*)d_in[9];
    const float* V1 = (const float*)d_in[10];
    const float* c1 = (const float*)d_in[11];
    const float* V2 = (const float*)d_in[12];
    const float* c2 = (const float*)d_in[13];
    const float* V3 = (const float*)d_in[14];
    const float* c3 = (const float*)d_in[15];
    const float* V4 = (const float*)d_in[16];
    const float* c4 = (const float*)d_in[17];

    float* out  = (float*)d_out;
    float* Xrec = out;                  // 16384*784  (bytes [0, 51,380,224))
    float* Zenc = out + 12845056;       // 16384*64
    float* Zdec = out + 13893632;       // 16384*64
    float* Zemb = out + 14942208;       // 512*64

    // ---- workspace layout (peak 98.9 MB; proven budget >= 118.0 MB) ----
    char* ws = (char*)d_ws;
    // [0, 52.4M): Xhi/Xlo -> h2h/h2l -> S -> g3
    ushort* Xhi = (ushort*)(ws + 0);           // 26,214,400
    ushort* Xlo = (ushort*)(ws + 26214400);    // -> 52,428,800
    ushort* h2h = (ushort*)(ws + 0);           // 16,777,216 (after enc1)
    ushort* h2l = (ushort*)(ws + 16777216);    // -> 33,554,432
    float*  S   = (float*)(ws + 0);            // 33,554,432 (after enc3)
    ushort* g3  = (ushort*)(ws + 0);           // 33,554,432 (after argmins)
    // [52.4M, 86.0M): h1l -> h3h/h3l -> g1/g2
    ushort* h1l = (ushort*)(ws + 52428800);    // 33,554,432
    ushort* h3h = (ushort*)(ws + 52428800);    // 12,582,912 (after enc2)
    ushort* h3l = (ushort*)(ws + 65011712);    // -> 77,594,624
    ushort* g1  = (ushort*)(ws + 52428800);    // 12,582,912 (after enc4)
    ushort* g2  = (ushort*)(ws + 65011712);    // 16,777,216 -> 81,788,928
    // h1h parks in d_out's Xrec slab (dead before dec4)
    ushort* h1h = (ushort*)d_out;              // 33,554,432 < 51,380,224
    // persistent tail
    float*  Zn2  = (float*)(ws + 85983232);
    float*  En2  = (float*)(ws + 86048768);
    ushort* Zdcb = (ushort*)(ws + 86050816);   // 2,097,152
    ushort* Wt1h = (ushort*)(ws + 88147968);   // 8p x 100kbg: 1,638,400
    ushort* Wt1l = (ushort*)(ws + 89786368);
    ushort* Wt2h = (ushort*)(ws + 91424768);   // 4p x 128: 1,048,576
    ushort* Wt2l = (ushort*)(ws + 92473344);
    ushort* Wt3h = (ushort*)(ws + 93521920);   // 3p x 64: 393,216
    ushort* Wt3l = (ushort*)(ws + 93915136);
    ushort* Wt4h = (ushort*)(ws + 94308352);   // 1p x 48: 98,304
    ushort* Wt4l = (ushort*)(ws + 94406656);
    ushort* Vt1  = (ushort*)(ws + 94504960);   // 3p x 8: 49,152
    ushort* Vt2  = (ushort*)(ws + 94554112);   // 4p x 48: 393,216
    ushort* Vt3  = (ushort*)(ws + 94947328);   // 8p x 64: 1,048,576
    ushort* Vt4  = (ushort*)(ws + 95995904);   // 7p x 128: 1,835,008 -> 97,830,912
    float*  Pv   = (float*)(ws + 97830912);    // 512 x 256 partial vals: 524,288
    int*    Pi   = (int*)  (ws + 98355200);    // 512 x 256 partial idxs: 524,288 -> 98,879,488

    const dim3 blk(256);

    // ---- conversion & tiling ----
    conv_x<<<dim3(2048), blk, 0, stream>>>(X, Xhi, Xlo);
    prep_w<true ><<<dim3(256), blk, 0, stream>>>(W1, Wt1h, Wt1l, 784, 1000, 100, 8);
    prep_w<true ><<<dim3(256), blk, 0, stream>>>(W2, Wt2h, Wt2l, 1000, 500, 128, 4);
    prep_w<true ><<<dim3(128), blk, 0, stream>>>(W3, Wt3h, Wt3l, 500, 300, 64, 3);
    prep_w<true ><<<dim3(64),  blk, 0, stream>>>(W4, Wt4h, Wt4l, 300, 64, 48, 1);
    prep_w<false><<<dim3(64),  blk, 0, stream>>>(V1, Vt1, nullptr, 64, 300, 8, 3);
    prep_w<false><<<dim3(128), blk, 0, stream>>>(V2, Vt2, nullptr, 300, 500, 48, 4);
    prep_w<false><<<dim3(256), blk, 0, stream>>>(V3, Vt3, nullptr, 500, 1000, 64, 8);
    prep_w<false><<<dim3(256), blk, 0, stream>>>(V4, Vt4, nullptr, 1000, 784, 128, 7);

    // ---- encoder: split-bf16 (3-MFMA) ----
    gemm_mfma<1, true, 2><<<dim3(8, 128), blk, 0, stream>>>(Xhi, Xlo, Wt1h, Wt1l, b1, nullptr, h1h, h1l, 100, 25, 1000);
    gemm_mfma<1, true, 2><<<dim3(4, 128), blk, 0, stream>>>(h1h, h1l, Wt2h, Wt2l, b2, nullptr, h2h, h2l, 128, 32, 500);
    gemm_mfma<1, true, 2><<<dim3(3, 128), blk, 0, stream>>>(h2h, h2l, Wt3h, Wt3l, b3, nullptr, h3h, h3l, 64, 16, 300);
    gemm_mfma<0, true, 0><<<dim3(1, 128), blk, 0, stream>>>(h3h, h3l, Wt4h, Wt4l, b4, Zenc, nullptr, nullptr, 48, 12, 64);

    // ---- nearest-neighbor (f32) ----
    row_norms64<<<dim3(8),  dim3(64), 0, stream>>>(E,    En2, 512);
    row_norms64<<<dim3(64), blk,      0, stream>>>(Zenc, Zn2, 16384);
    gemm_f32_bt<<<dim3(8, 256), blk, 0, stream>>>(Zenc, E, S, 16384, 64, 512);
    argmin_rows<<<dim3(4096), blk, 0, stream>>>(S, En2, E, Zdec, Zdcb);
    argmin_cols_p1<<<dim3(256), blk, 0, stream>>>(S, Zn2, Pv, Pi);
    argmin_cols_p2<<<dim3(512), blk, 0, stream>>>(Pv, Pi, Zenc, Zemb);

    // ---- decoder: plain bf16 MFMA ----
    gemm_mfma<2, false, 1><<<dim3(3, 128), blk, 0, stream>>>(Zdcb, nullptr, Vt1, nullptr, c1, nullptr, g1, nullptr, 8, 2, 300);
    gemm_mfma<2, false, 1><<<dim3(4, 128), blk, 0, stream>>>(g1, nullptr, Vt2, nullptr, c2, nullptr, g2, nullptr, 48, 12, 500);
    gemm_mfma<2, false, 1><<<dim3(8, 128), blk, 0, stream>>>(g2, nullptr, Vt3, nullptr, c3, nullptr, g3, nullptr, 64, 16, 1000);
    gemm_mfma<3, false, 0><<<dim3(7, 128), blk, 0, stream>>>(g3, nullptr, Vt4, nullptr, c4, Xrec, nullptr, nullptr, 128, 32, 784);
}